// Round 7
// baseline (151.805 us; speedup 1.0000x reference)
//
#include <hip/hip_runtime.h>

typedef unsigned short ushort;
typedef short bf16x8 __attribute__((ext_vector_type(8)));   // 8 bf16 in 4 VGPRs
typedef float f32x4 __attribute__((ext_vector_type(4)));

static __device__ __forceinline__ ushort f2b(float f) {
  unsigned u = __builtin_bit_cast(unsigned, f);
  u = (u + 0x7fffu + ((u >> 16) & 1u)) >> 16;
  return (ushort)u;
}
static __device__ __forceinline__ float b2f(ushort b) {
  return __builtin_bit_cast(float, (unsigned)b << 16);
}

// async global->LDS, 16B per lane; LDS dest is wave-uniform base + lane*16
static __device__ __forceinline__ void gll16(const ushort* g, ushort* l) {
  __builtin_amdgcn_global_load_lds(
      (const __attribute__((address_space(1))) void*)g,
      (__attribute__((address_space(3))) void*)l, 16, 0, 0);
}

// ---------------------------------------------------------------------------
// prep: LDS-tiled 32x32 transpose for all five fp32->bf16 transposes.
// ---------------------------------------------------------------------------
__global__ __launch_bounds__(256) void prep_kernel(
    const float* __restrict__ x,
    const float* __restrict__ w_qkv, const float* __restrict__ w_proj,
    const float* __restrict__ w_fc1, const float* __restrict__ w_fc2,
    ushort* __restrict__ xb, ushort* __restrict__ wqkvT,
    ushort* __restrict__ wprojT, ushort* __restrict__ wfc1T,
    ushort* __restrict__ wfc2T)
{
  __shared__ float tile[32][33];
  int t = blockIdx.x;
  const float* src; ushort* dst; int R, Nc, r0, c0;
  if (t < 2048)              { src = x;      dst = xb;     R = 256; Nc = 8192; r0 = (t >> 8) * 32; c0 = (t & 255) * 32; }
  else if ((t -= 2048) < 192){ src = w_qkv;  dst = wqkvT;  R = 256; Nc = 768;  r0 = (t / 24) * 32; c0 = (t % 24) * 32; }
  else if ((t -= 192) < 64)  { src = w_proj; dst = wprojT; R = 256; Nc = 256;  r0 = (t / 8) * 32;  c0 = (t % 8) * 32; }
  else if ((t -= 64) < 128)  { src = w_fc1;  dst = wfc1T;  R = 256; Nc = 512;  r0 = (t / 16) * 32; c0 = (t % 16) * 32; }
  else           { t -= 128;   src = w_fc2;  dst = wfc2T;  R = 512; Nc = 256;  r0 = (t / 8) * 32;  c0 = (t % 8) * 32; }

  const int tx = threadIdx.x & 31, ty = threadIdx.x >> 5;
  #pragma unroll
  for (int i = 0; i < 4; i++)
    tile[ty + i * 8][tx] = src[(size_t)(r0 + ty + i * 8) * Nc + c0 + tx];
  __syncthreads();
  #pragma unroll
  for (int i = 0; i < 4; i++)
    dst[(size_t)(c0 + ty + i * 8) * R + r0 + tx] = f2b(tile[tx][ty + i * 8]);
}

// ---------------------------------------------------------------------------
// MFMA bf16 GEMM, 64x64 tile, 4 waves, BK=128 (v2 engine, gll16 staging).
// Used only for the qkv GEMM (EPI 0):
//   q,k rows to C0[m*N+n]; v (n>=512) -> C1 vT[(n-512)*8192+m]
// ---------------------------------------------------------------------------
template<int EPI, int KD>
__global__ __launch_bounds__(256) void gemm_mfma(
    const ushort* __restrict__ A, const ushort* __restrict__ Bt,
    const float* __restrict__ bias, const float* __restrict__ R,
    const ushort* __restrict__ RS,
    void* __restrict__ C0, void* __restrict__ C1,
    int M, int N)
{
  __shared__ __attribute__((aligned(16))) ushort As[64 * 128];
  __shared__ __attribute__((aligned(16))) ushort Bs[64 * 128];

  const int bm = blockIdx.y * 64;
  const int bn = blockIdx.x * 64;
  const int t  = threadIdx.x;
  const int w    = t >> 6;
  const int lane = t & 63;
  const int wm = (w & 1) * 32;
  const int wn = (w >> 1) * 32;
  const int lm = lane & 15;
  const int kq = lane >> 4;                     // 0..3

  const int rl  = lane >> 4;                    // row within chunk
  const int cbx = (lane & 15) << 4;             // byte col within row
  const int xr  = (lm & 7) << 4;                // read-side XOR

  f32x4 acc[2][2] = {};

  #pragma unroll
  for (int k0 = 0; k0 < KD; k0 += 128) {
    #pragma unroll
    for (int s = 0; s < 4; s++) {
      const int c = w * 4 + s;
      const int r = c * 4 + rl;                                // tile row 0..63
      const int off = (cbx ^ ((r & 7) << 4)) >> 1;             // swizzled src (ushorts)
      gll16(A  + (size_t)(bm + r) * KD + k0 + off, As + c * 512);
      gll16(Bt + (size_t)(bn + r) * KD + k0 + off, Bs + c * 512);
    }
    __syncthreads();

    #pragma unroll
    for (int ks = 0; ks < 4; ks++) {
      const int kb = ks * 64 + (kq << 4);       // byte offset within row
      const int cs = kb ^ xr;                   // swizzled read col (bytes)
      bf16x8 a0 = *(const bf16x8*)((const char*)As + (wm + lm)      * 256 + cs);
      bf16x8 a1 = *(const bf16x8*)((const char*)As + (wm + 16 + lm) * 256 + cs);
      bf16x8 b0 = *(const bf16x8*)((const char*)Bs + (wn + lm)      * 256 + cs);
      bf16x8 b1 = *(const bf16x8*)((const char*)Bs + (wn + 16 + lm) * 256 + cs);
      acc[0][0] = __builtin_amdgcn_mfma_f32_16x16x32_bf16(a0, b0, acc[0][0], 0, 0, 0);
      acc[0][1] = __builtin_amdgcn_mfma_f32_16x16x32_bf16(a0, b1, acc[0][1], 0, 0, 0);
      acc[1][0] = __builtin_amdgcn_mfma_f32_16x16x32_bf16(a1, b0, acc[1][0], 0, 0, 0);
      acc[1][1] = __builtin_amdgcn_mfma_f32_16x16x32_bf16(a1, b1, acc[1][1], 0, 0, 0);
    }
    __syncthreads();
  }

  #pragma unroll
  for (int ti = 0; ti < 2; ti++) {
    #pragma unroll
    for (int tj = 0; tj < 2; tj++) {
      const int n  = bn + wn + tj * 16 + lm;
      const int m0 = bm + wm + ti * 16 + kq * 4;
      if (EPI == 0) {
        if (n < 512) {
          #pragma unroll
          for (int r = 0; r < 4; r++)
            ((ushort*)C0)[(size_t)(m0 + r) * N + n] = f2b(acc[ti][tj][r] + bias[n]);
        } else {
          ushort4 st;
          st.x = f2b(acc[ti][tj][0] + bias[n]);
          st.y = f2b(acc[ti][tj][1] + bias[n]);
          st.z = f2b(acc[ti][tj][2] + bias[n]);
          st.w = f2b(acc[ti][tj][3] + bias[n]);
          *(ushort4*)((ushort*)C1 + (size_t)(n - 512) * 8192 + m0) = st;
        }
      }
    }
  }
}

// ---------------------------------------------------------------------------
// MFMA neighborhood attention v3 (unchanged).
// ---------------------------------------------------------------------------
__global__ __launch_bounds__(256, 4) void natt_mfma(
    const ushort* __restrict__ qkv, const ushort* __restrict__ vT,
    const float* __restrict__ rpb, ushort* __restrict__ att)
{
  __shared__ __attribute__((aligned(16))) ushort Plds[4][7][16][40];
  __shared__ float Rlds[4][176];

  const int w    = threadIdx.x >> 6;
  const int lane = threadIdx.x & 63;
  const int l  = lane & 15;
  const int q  = lane >> 4;
  const int tile = blockIdx.x;            // 0..511
  const int n    = blockIdx.y * 4 + w;    // head 0..7
  const int ph  = tile >> 3;
  const int pw0 = (tile & 7) << 4;
  const int p0  = ph * 128 + pw0;

  int sh = ph - 3;  sh = sh < 0 ? 0 : (sh > 57 ? 57 : sh);
  int sb = pw0 - 3; sb = sb < 0 ? 0 : sb;
  const int sba = sb & ~7;                // 16B-aligned span base

  const float L2E = 1.44269504f;
  for (int idx = lane; idx < 169; idx += 64)
    Rlds[w][idx] = rpb[n * 169 + idx] * L2E;

  bf16x8 qf = *(const bf16x8*)(qkv + (size_t)(p0 + l) * 768 + n * 32 + q * 8);

  const float KSC = 0.17677669529663689f * 1.44269504f;  // hd^-0.5 * log2(e)
  const int relh0 = sh - ph + 6;          // 0..6
  float rsum[4] = {0.f, 0.f, 0.f, 0.f};

  #pragma unroll
  for (int h = 0; h < 2; h++) {
    f32x4 s[7] = {};
    #pragma unroll
    for (int i = 0; i < 7; i++) {
      const int rowp = (sh + i) * 128;
      int jc = sba + h * 16 + l;
      jc = jc > 127 ? 127 : jc;           // clamp addr; junk masked below
      bf16x8 kf = *(const bf16x8*)(qkv + (size_t)(rowp + jc) * 768 + 256 + n * 32 + q * 8);
      s[i] = __builtin_amdgcn_mfma_f32_16x16x32_bf16(qf, kf, s[i], 0, 0, 0);
    }
    #pragma unroll
    for (int r = 0; r < 4; r++) {
      const int pw = pw0 + q * 4 + r;
      int sw = pw - 3; sw = sw < 0 ? 0 : (sw > 121 ? 121 : sw);
      const int jc = sba + h * 16 + l;
      const bool valid = (unsigned)(jc - sw) <= 6u;
      int relw = jc - pw + 6;
      relw = relw < 0 ? 0 : (relw > 12 ? 12 : relw);
      #pragma unroll
      for (int i = 0; i < 7; i++) {
        float b = Rlds[w][(relh0 + i) * 13 + relw];
        float v = s[i][r] * KSC + b;
        v = valid ? v : -1e30f;
        float e = exp2f(v);
        rsum[r] += e;
        Plds[w][i][q * 4 + r][h * 16 + l] = f2b(e);
      }
    }
  }

  #pragma unroll
  for (int r = 0; r < 4; r++) {
    rsum[r] += __shfl_xor(rsum[r], 1);
    rsum[r] += __shfl_xor(rsum[r], 2);
    rsum[r] += __shfl_xor(rsum[r], 4);
    rsum[r] += __shfl_xor(rsum[r], 8);
  }

  f32x4 o[2] = {};
  #pragma unroll
  for (int i = 0; i < 7; i++) {
    bf16x8 pf = *(const bf16x8*)(&Plds[w][i][l][q * 8]);
    const int rowp = (sh + i) * 128;
    #pragma unroll
    for (int dh = 0; dh < 2; dh++) {
      bf16x8 vf = *(const bf16x8*)(vT + (size_t)(n * 32 + dh * 16 + l) * 8192
                                      + rowp + sba + q * 8);
      o[dh] = __builtin_amdgcn_mfma_f32_16x16x32_bf16(pf, vf, o[dh], 0, 0, 0);
    }
  }

  #pragma unroll
  for (int r = 0; r < 4; r++) {
    const float inv = 1.0f / rsum[r];
    #pragma unroll
    for (int dh = 0; dh < 2; dh++)
      att[(size_t)(p0 + q * 4 + r) * 256 + n * 32 + dh * 16 + l] = f2b(o[dh][r] * inv);
  }
}

// ---------------------------------------------------------------------------
// Fused proj + fc1(gelu) + fc2 + both residuals, v6: batched register loads.
// v5 postmortem: VGPR_Count=52 -> compiler kept only ~4 loads in flight and
// serialized load->mfma per k-step; kernel is latency-bound on cold-cache
// weight fetches (all four schedule variants pinned at 46us, all pipes idle).
// v6 forces memory-level parallelism: per phase, ALL 16 B-fragments (+8 A)
// are loaded into named register arrays back-to-back (sched_barrier keeps
// the batch together), THEN the 16 MFMAs run. ~24 loads in flight per wave
// x 16 waves/CU. Grid/LDS/barriers identical to v5.
// ---------------------------------------------------------------------------
__global__ __launch_bounds__(512, 4) void mlp_fused(
    const ushort* __restrict__ att, const ushort* __restrict__ wprojT,
    const ushort* __restrict__ wfc1T, const ushort* __restrict__ wfc2T,
    const float* __restrict__ b_proj, const float* __restrict__ b_fc1,
    const float* __restrict__ b_fc2, const float* __restrict__ xres,
    float* __restrict__ out)
{
  __shared__ __attribute__((aligned(16))) ushort X1[16 * 256];   // 8KB, swz
  __shared__ __attribute__((aligned(16))) ushort Hs[16 * 256];   // 8KB, swz

  const int bm   = blockIdx.x * 16;
  const int w    = threadIdx.x >> 6;
  const int lane = threadIdx.x & 63;
  const int lm   = lane & 15;
  const int kq   = lane >> 4;          // 0..3
  const int wn   = w * 32;             // wave col base 0..224
  const int n0   = wn + lm;
  const int n1   = wn + 16 + lm;

  // ---------------- proj: x1 = att @ wprojT^T + b_proj + x(chw) ------------
  {
    bf16x8 b0[8], b1[8], aP[8];
    #pragma unroll
    for (int kk = 0; kk < 8; kk++) {
      const int ko = kk * 32 + kq * 8;
      b0[kk] = *(const bf16x8*)(wprojT + (size_t)n0 * 256 + ko);
      b1[kk] = *(const bf16x8*)(wprojT + (size_t)n1 * 256 + ko);
      aP[kk] = *(const bf16x8*)(att + (size_t)(bm + lm) * 256 + ko);
    }
    __builtin_amdgcn_sched_barrier(0);   // keep the 24-load batch issued first

    f32x4 acc0 = {}, acc1 = {};
    #pragma unroll
    for (int kk = 0; kk < 8; kk++) {
      acc0 = __builtin_amdgcn_mfma_f32_16x16x32_bf16(aP[kk], b0[kk], acc0, 0, 0, 0);
      acc1 = __builtin_amdgcn_mfma_f32_16x16x32_bf16(aP[kk], b1[kk], acc1, 0, 0, 0);
    }
    // epilogue: + b_proj + x residual -> X1 (swizzled)
    const float bp0 = b_proj[n0], bp1 = b_proj[n1];
    float4 xr0 = *(const float4*)(xres + (size_t)n0 * 8192 + bm + kq * 4);
    float4 xr1 = *(const float4*)(xres + (size_t)n1 * 8192 + bm + kq * 4);
    const float* x0 = &xr0.x; const float* x1 = &xr1.x;
    #pragma unroll
    for (int r = 0; r < 4; r++) {
      const int m = kq * 4 + r;
      X1[m * 256 + (n0 ^ ((m & 7) << 3))] = f2b(acc0[r] + bp0 + x0[r]);
      X1[m * 256 + (n1 ^ ((m & 7) << 3))] = f2b(acc1[r] + bp1 + x1[r]);
    }
  }
  __syncthreads();

  // ------------- fc1 (gelu) + fc2, two 256-col hidden halves --------------
  f32x4 acco0 = {}, acco1 = {};
  #pragma unroll
  for (int hf = 0; hf < 2; hf++) {
    {
      bf16x8 b0[8], b1[8];
      #pragma unroll
      for (int kk = 0; kk < 8; kk++) {
        const int ko = kk * 32 + kq * 8;
        b0[kk] = *(const bf16x8*)(wfc1T + (size_t)(hf * 256 + n0) * 256 + ko);
        b1[kk] = *(const bf16x8*)(wfc1T + (size_t)(hf * 256 + n1) * 256 + ko);
      }
      __builtin_amdgcn_sched_barrier(0);

      f32x4 acch0 = {}, acch1 = {};
      #pragma unroll
      for (int kk = 0; kk < 8; kk++) {
        const int ko = kk * 32 + kq * 8;
        bf16x8 a = *(const bf16x8*)(&X1[lm * 256 + (ko ^ ((lm & 7) << 3))]);
        acch0 = __builtin_amdgcn_mfma_f32_16x16x32_bf16(a, b0[kk], acch0, 0, 0, 0);
        acch1 = __builtin_amdgcn_mfma_f32_16x16x32_bf16(a, b1[kk], acch1, 0, 0, 0);
      }
      const float g0 = b_fc1[hf * 256 + n0], g1 = b_fc1[hf * 256 + n1];
      #pragma unroll
      for (int r = 0; r < 4; r++) {
        const int m = kq * 4 + r;
        float v0 = acch0[r] + g0;
        v0 = 0.5f * v0 * (1.0f + erff(v0 * 0.70710678118f));
        Hs[m * 256 + (n0 ^ ((m & 7) << 3))] = f2b(v0);
        float v1 = acch1[r] + g1;
        v1 = 0.5f * v1 * (1.0f + erff(v1 * 0.70710678118f));
        Hs[m * 256 + (n1 ^ ((m & 7) << 3))] = f2b(v1);
      }
    }
    __syncthreads();                               // Hs(hf) complete

    {
      bf16x8 b0[8], b1[8];
      #pragma unroll
      for (int kk = 0; kk < 8; kk++) {
        const int ko = kk * 32 + kq * 8;
        b0[kk] = *(const bf16x8*)(wfc2T + (size_t)n0 * 512 + hf * 256 + ko);
        b1[kk] = *(const bf16x8*)(wfc2T + (size_t)n1 * 512 + hf * 256 + ko);
      }
      __builtin_amdgcn_sched_barrier(0);

      #pragma unroll
      for (int kk = 0; kk < 8; kk++) {
        const int ko = kk * 32 + kq * 8;
        bf16x8 a = *(const bf16x8*)(&Hs[lm * 256 + (ko ^ ((lm & 7) << 3))]);
        acco0 = __builtin_amdgcn_mfma_f32_16x16x32_bf16(a, b0[kk], acco0, 0, 0, 0);
        acco1 = __builtin_amdgcn_mfma_f32_16x16x32_bf16(a, b1[kk], acco1, 0, 0, 0);
      }
    }
    __syncthreads();                               // Hs reads done before overwrite
  }

  // ---------------- fc2 epilogue: + b_fc2 + x1 residual, f32 chw -----------
  const float c0 = b_fc2[n0], c1 = b_fc2[n1];
  float4 v0, v1;
  float* p0 = &v0.x; float* p1 = &v1.x;
  #pragma unroll
  for (int r = 0; r < 4; r++) {
    const int m = kq * 4 + r;
    p0[r] = acco0[r] + c0 + b2f(X1[m * 256 + (n0 ^ ((m & 7) << 3))]);
    p1[r] = acco1[r] + c1 + b2f(X1[m * 256 + (n1 ^ ((m & 7) << 3))]);
  }
  *(float4*)(out + (size_t)n0 * 8192 + bm + kq * 4) = v0;
  *(float4*)(out + (size_t)n1 * 8192 + bm + kq * 4) = v1;
}

// ---------------------------------------------------------------------------
extern "C" void kernel_launch(void* const* d_in, const int* in_sizes, int n_in,
                              void* d_out, int out_size, void* d_ws, size_t ws_size,
                              hipStream_t stream)
{
  const float* x      = (const float*)d_in[0];
  const float* w_qkv  = (const float*)d_in[1];
  const float* b_qkv  = (const float*)d_in[2];
  const float* rpb    = (const float*)d_in[3];
  const float* w_proj = (const float*)d_in[4];
  const float* b_proj = (const float*)d_in[5];
  const float* w_fc1  = (const float*)d_in[6];
  const float* b_fc1  = (const float*)d_in[7];
  const float* w_fc2  = (const float*)d_in[8];
  const float* b_fc2  = (const float*)d_in[9];
  float* out = (float*)d_out;

  const int M = 8192;
  char* ws = (char*)d_ws;
  ushort* xb     = (ushort*)(ws);               //  4,194,304 B (reused as att)
  ushort* qkv    = (ushort*)(ws + 4194304);     // 12,582,912 B
  ushort* wqkvT  = (ushort*)(ws + 20971520);    //    393,216 B
  ushort* wprojT = (ushort*)(ws + 21364736);    //    131,072 B
  ushort* wfc1T  = (ushort*)(ws + 21495808);    //    262,144 B
  ushort* wfc2T  = (ushort*)(ws + 21757952);    //    262,144 B
  ushort* vT     = (ushort*)(ws + 22020096);    //  4,194,304 B + 64K pad
  ushort* att = xb;                             // xb dead after qkv GEMM

  dim3 blk(256);

  prep_kernel<<<dim3(2560), blk, 0, stream>>>(
      x, w_qkv, w_proj, w_fc1, w_fc2, xb, wqkvT, wprojT, wfc1T, wfc2T);

  // qkv = xb @ wqkvT^T + b_qkv  -> q,k rows + transposed vT
  gemm_mfma<0, 256><<<dim3(768 / 64, M / 64), blk, 0, stream>>>(
      xb, wqkvT, b_qkv, nullptr, nullptr, qkv, vT, M, 768);

  natt_mfma<<<dim3(512, 2), blk, 0, stream>>>(qkv, vT, rpb, att);

  // out = fc2(gelu(fc1(proj(att)+x))) + x1, one kernel, batched reg loads
  mlp_fused<<<dim3(512), dim3(512), 0, stream>>>(
      att, wprojT, wfc1T, wfc2T, b_proj, b_fc1, b_fc2, x, out);
}

// Round 8
// 136.864 us; speedup vs baseline: 1.1092x; 1.1092x over previous
//
#include <hip/hip_runtime.h>

typedef unsigned short ushort;
typedef short bf16x8 __attribute__((ext_vector_type(8)));   // 8 bf16 in 4 VGPRs
typedef float f32x4 __attribute__((ext_vector_type(4)));

static __device__ __forceinline__ ushort f2b(float f) {
  unsigned u = __builtin_bit_cast(unsigned, f);
  u = (u + 0x7fffu + ((u >> 16) & 1u)) >> 16;
  return (ushort)u;
}
static __device__ __forceinline__ float b2f(ushort b) {
  return __builtin_bit_cast(float, (unsigned)b << 16);
}

// async global->LDS, 16B per lane; zero VGPR cost for the returning data.
static __device__ __forceinline__ void gll16(const ushort* g, ushort* l) {
  __builtin_amdgcn_global_load_lds(
      (const __attribute__((address_space(1))) void*)g,
      (__attribute__((address_space(3))) void*)l, 16, 0, 0);
}

// counted wait + raw barrier: keeps the remaining prefetch queue in flight
// across the barrier (the whole point -- __syncthreads would drain vmcnt(0)).
#define SWAIT(N)                                                            \
  asm volatile("s_waitcnt vmcnt(" #N ")" ::: "memory");                     \
  __builtin_amdgcn_s_barrier();                                             \
  __builtin_amdgcn_sched_barrier(0)

// ---------------------------------------------------------------------------
// prep: LDS-tiled 32x32 transpose for all five fp32->bf16 transposes.
// ---------------------------------------------------------------------------
__global__ __launch_bounds__(256) void prep_kernel(
    const float* __restrict__ x,
    const float* __restrict__ w_qkv, const float* __restrict__ w_proj,
    const float* __restrict__ w_fc1, const float* __restrict__ w_fc2,
    ushort* __restrict__ xb, ushort* __restrict__ wqkvT,
    ushort* __restrict__ wprojT, ushort* __restrict__ wfc1T,
    ushort* __restrict__ wfc2T)
{
  __shared__ float tile[32][33];
  int t = blockIdx.x;
  const float* src; ushort* dst; int R, Nc, r0, c0;
  if (t < 2048)              { src = x;      dst = xb;     R = 256; Nc = 8192; r0 = (t >> 8) * 32; c0 = (t & 255) * 32; }
  else if ((t -= 2048) < 192){ src = w_qkv;  dst = wqkvT;  R = 256; Nc = 768;  r0 = (t / 24) * 32; c0 = (t % 24) * 32; }
  else if ((t -= 192) < 64)  { src = w_proj; dst = wprojT; R = 256; Nc = 256;  r0 = (t / 8) * 32;  c0 = (t % 8) * 32; }
  else if ((t -= 64) < 128)  { src = w_fc1;  dst = wfc1T;  R = 256; Nc = 512;  r0 = (t / 16) * 32; c0 = (t % 16) * 32; }
  else           { t -= 128;   src = w_fc2;  dst = wfc2T;  R = 512; Nc = 256;  r0 = (t / 8) * 32;  c0 = (t % 8) * 32; }

  const int tx = threadIdx.x & 31, ty = threadIdx.x >> 5;
  #pragma unroll
  for (int i = 0; i < 4; i++)
    tile[ty + i * 8][tx] = src[(size_t)(r0 + ty + i * 8) * Nc + c0 + tx];
  __syncthreads();
  #pragma unroll
  for (int i = 0; i < 4; i++)
    dst[(size_t)(c0 + ty + i * 8) * R + r0 + tx] = f2b(tile[tx][ty + i * 8]);
}

// ---------------------------------------------------------------------------
// Streaming MFMA GEMM, 64x64 tile, 4 waves, BK=128, FULL-K PREFETCH.
// All S=KD/128 K-steps' staging (8 gll16/wave/step) is issued up front
// (S=2) or 2-ahead (S=4, 3-buffer rotation); per step the wave waits only
// vmcnt(8*(steps_still_in_flight)) -- never 0 until the last -- so the
// prefetch queue streams continuously. gll16 costs no VGPRs -> 64-128KB
// in flight per block vs the ~8KB a VGPR pipeline sustains.
// EPI 0: qkv -> q,k rows to C0[m*N+n]; v (n>=512) -> C1 vT[(n-512)*8192+m]
// EPI 1: proj  -> v += R[n*M+m] (fp32 x chw); C0 x1b[m*256+n] = bf16(v)
// EPI 2: fc1   -> gelu(v) -> bf16 C0[m*N+n]
// EPI 3: fc2   -> v += b2f(RS[m*256+n]); C0 out[n*M+m] = v (f32 chw, float4)
// ---------------------------------------------------------------------------
template<int EPI, int KD>
__global__ __launch_bounds__(256) void gemm_stream(
    const ushort* __restrict__ A, const ushort* __restrict__ Bt,
    const float* __restrict__ bias, const float* __restrict__ R,
    const ushort* __restrict__ RS,
    void* __restrict__ C0, void* __restrict__ C1,
    int M, int N)
{
  constexpr int S  = KD / 128;          // K-steps
  constexpr int NB = (S < 3) ? S : 3;   // LDS slots (S=2 -> 64KB, S=4 -> 96KB)
  __shared__ __attribute__((aligned(16))) ushort As[NB][64 * 128];
  __shared__ __attribute__((aligned(16))) ushort Bs[NB][64 * 128];

  const int bm = blockIdx.y * 64;
  const int bn = blockIdx.x * 64;
  const int t  = threadIdx.x;
  const int w    = t >> 6;
  const int lane = t & 63;
  const int wm = (w & 1) * 32;
  const int wn = (w >> 1) * 32;
  const int lm = lane & 15;
  const int kq = lane >> 4;                     // 0..3

  const int rl  = lane >> 4;                    // row within 1KB chunk
  const int cbx = (lane & 15) << 4;             // byte col within row
  const int xr  = (lm & 7) << 4;                // read-side XOR

  f32x4 acc[2][2] = {};

  // stage K-step `step` into slot `slot`: exactly 8 gll16 per wave, in order
  auto stage = [&](int slot, int step) {
    #pragma unroll
    for (int j = 0; j < 4; j++) {
      const int c = w * 4 + j;
      const int r = c * 4 + rl;                              // tile row 0..63
      const int off = (cbx ^ ((r & 7) << 4)) >> 1;           // swz src (ushorts)
      gll16(A  + (size_t)(bm + r) * KD + step * 128 + off, &As[slot][c * 512]);
      gll16(Bt + (size_t)(bn + r) * KD + step * 128 + off, &Bs[slot][c * 512]);
    }
  };
  auto compute = [&](int slot) {
    #pragma unroll
    for (int ks = 0; ks < 4; ks++) {
      const int kb = ks * 64 + (kq << 4);       // byte offset within row
      const int cs = kb ^ xr;                   // swizzled read col (bytes)
      bf16x8 a0 = *(const bf16x8*)((const char*)&As[slot][0] + (wm + lm)      * 256 + cs);
      bf16x8 a1 = *(const bf16x8*)((const char*)&As[slot][0] + (wm + 16 + lm) * 256 + cs);
      bf16x8 b0 = *(const bf16x8*)((const char*)&Bs[slot][0] + (wn + lm)      * 256 + cs);
      bf16x8 b1 = *(const bf16x8*)((const char*)&Bs[slot][0] + (wn + 16 + lm) * 256 + cs);
      acc[0][0] = __builtin_amdgcn_mfma_f32_16x16x32_bf16(a0, b0, acc[0][0], 0, 0, 0);
      acc[0][1] = __builtin_amdgcn_mfma_f32_16x16x32_bf16(a0, b1, acc[0][1], 0, 0, 0);
      acc[1][0] = __builtin_amdgcn_mfma_f32_16x16x32_bf16(a1, b0, acc[1][0], 0, 0, 0);
      acc[1][1] = __builtin_amdgcn_mfma_f32_16x16x32_bf16(a1, b1, acc[1][1], 0, 0, 0);
    }
  };

  // prologue: 2 steps in flight (16 gll16/wave)
  stage(0, 0);
  if (S > 1) stage(1, 1);

  // steady state: wait(8) -> barrier -> [stage s+2] -> compute s; last: wait(0)
  #pragma unroll
  for (int s = 0; s < S; s++) {
    if (s < S - 1) { SWAIT(8); } else { SWAIT(0); }
    if (s + 2 < S) stage((s + 2) % NB, s + 2);   // slot certified free by barrier
    compute(s % NB);
  }

  #pragma unroll
  for (int ti = 0; ti < 2; ti++) {
    #pragma unroll
    for (int tj = 0; tj < 2; tj++) {
      const int n  = bn + wn + tj * 16 + lm;
      const int m0 = bm + wm + ti * 16 + kq * 4;
      if (EPI == 3) {
        float4 v;
        float* vp = &v.x;
        #pragma unroll
        for (int r = 0; r < 4; r++)
          vp[r] = acc[ti][tj][r] + bias[n] + b2f(RS[(size_t)(m0 + r) * 256 + n]);
        *(float4*)((float*)C0 + (size_t)n * M + m0) = v;
      } else if (EPI == 0) {
        if (n < 512) {
          #pragma unroll
          for (int r = 0; r < 4; r++)
            ((ushort*)C0)[(size_t)(m0 + r) * N + n] = f2b(acc[ti][tj][r] + bias[n]);
        } else {
          ushort4 st;
          st.x = f2b(acc[ti][tj][0] + bias[n]);
          st.y = f2b(acc[ti][tj][1] + bias[n]);
          st.z = f2b(acc[ti][tj][2] + bias[n]);
          st.w = f2b(acc[ti][tj][3] + bias[n]);
          *(ushort4*)((ushort*)C1 + (size_t)(n - 512) * 8192 + m0) = st;
        }
      } else {
        #pragma unroll
        for (int r = 0; r < 4; r++) {
          const int m = m0 + r;
          float v = acc[ti][tj][r] + bias[n];
          if (EPI == 1) {
            v += R[(size_t)n * M + m];
            ((ushort*)C0)[(size_t)m * 256 + n] = f2b(v);
          } else {  // EPI 2
            v = 0.5f * v * (1.0f + erff(v * 0.70710678118f));
            ((ushort*)C0)[(size_t)m * N + n] = f2b(v);
          }
        }
      }
    }
  }
}

// ---------------------------------------------------------------------------
// MFMA neighborhood attention v3 (unchanged).
// ---------------------------------------------------------------------------
__global__ __launch_bounds__(256, 4) void natt_mfma(
    const ushort* __restrict__ qkv, const ushort* __restrict__ vT,
    const float* __restrict__ rpb, ushort* __restrict__ att)
{
  __shared__ __attribute__((aligned(16))) ushort Plds[4][7][16][40];
  __shared__ float Rlds[4][176];

  const int w    = threadIdx.x >> 6;
  const int lane = threadIdx.x & 63;
  const int l  = lane & 15;
  const int q  = lane >> 4;
  const int tile = blockIdx.x;            // 0..511
  const int n    = blockIdx.y * 4 + w;    // head 0..7
  const int ph  = tile >> 3;
  const int pw0 = (tile & 7) << 4;
  const int p0  = ph * 128 + pw0;

  int sh = ph - 3;  sh = sh < 0 ? 0 : (sh > 57 ? 57 : sh);
  int sb = pw0 - 3; sb = sb < 0 ? 0 : sb;
  const int sba = sb & ~7;                // 16B-aligned span base

  const float L2E = 1.44269504f;
  for (int idx = lane; idx < 169; idx += 64)
    Rlds[w][idx] = rpb[n * 169 + idx] * L2E;

  bf16x8 qf = *(const bf16x8*)(qkv + (size_t)(p0 + l) * 768 + n * 32 + q * 8);

  const float KSC = 0.17677669529663689f * 1.44269504f;  // hd^-0.5 * log2(e)
  const int relh0 = sh - ph + 6;          // 0..6
  float rsum[4] = {0.f, 0.f, 0.f, 0.f};

  #pragma unroll
  for (int h = 0; h < 2; h++) {
    f32x4 s[7] = {};
    #pragma unroll
    for (int i = 0; i < 7; i++) {
      const int rowp = (sh + i) * 128;
      int jc = sba + h * 16 + l;
      jc = jc > 127 ? 127 : jc;           // clamp addr; junk masked below
      bf16x8 kf = *(const bf16x8*)(qkv + (size_t)(rowp + jc) * 768 + 256 + n * 32 + q * 8);
      s[i] = __builtin_amdgcn_mfma_f32_16x16x32_bf16(qf, kf, s[i], 0, 0, 0);
    }
    #pragma unroll
    for (int r = 0; r < 4; r++) {
      const int pw = pw0 + q * 4 + r;
      int sw = pw - 3; sw = sw < 0 ? 0 : (sw > 121 ? 121 : sw);
      const int jc = sba + h * 16 + l;
      const bool valid = (unsigned)(jc - sw) <= 6u;
      int relw = jc - pw + 6;
      relw = relw < 0 ? 0 : (relw > 12 ? 12 : relw);
      #pragma unroll
      for (int i = 0; i < 7; i++) {
        float b = Rlds[w][(relh0 + i) * 13 + relw];
        float v = s[i][r] * KSC + b;
        v = valid ? v : -1e30f;
        float e = exp2f(v);
        rsum[r] += e;
        Plds[w][i][q * 4 + r][h * 16 + l] = f2b(e);
      }
    }
  }

  #pragma unroll
  for (int r = 0; r < 4; r++) {
    rsum[r] += __shfl_xor(rsum[r], 1);
    rsum[r] += __shfl_xor(rsum[r], 2);
    rsum[r] += __shfl_xor(rsum[r], 4);
    rsum[r] += __shfl_xor(rsum[r], 8);
  }

  f32x4 o[2] = {};
  #pragma unroll
  for (int i = 0; i < 7; i++) {
    bf16x8 pf = *(const bf16x8*)(&Plds[w][i][l][q * 8]);
    const int rowp = (sh + i) * 128;
    #pragma unroll
    for (int dh = 0; dh < 2; dh++) {
      bf16x8 vf = *(const bf16x8*)(vT + (size_t)(n * 32 + dh * 16 + l) * 8192
                                      + rowp + sba + q * 8);
      o[dh] = __builtin_amdgcn_mfma_f32_16x16x32_bf16(pf, vf, o[dh], 0, 0, 0);
    }
  }

  #pragma unroll
  for (int r = 0; r < 4; r++) {
    const float inv = 1.0f / rsum[r];
    #pragma unroll
    for (int dh = 0; dh < 2; dh++)
      att[(size_t)(p0 + q * 4 + r) * 256 + n * 32 + dh * 16 + l] = f2b(o[dh][r] * inv);
  }
}

// ---------------------------------------------------------------------------
extern "C" void kernel_launch(void* const* d_in, const int* in_sizes, int n_in,
                              void* d_out, int out_size, void* d_ws, size_t ws_size,
                              hipStream_t stream)
{
  const float* x      = (const float*)d_in[0];
  const float* w_qkv  = (const float*)d_in[1];
  const float* b_qkv  = (const float*)d_in[2];
  const float* rpb    = (const float*)d_in[3];
  const float* w_proj = (const float*)d_in[4];
  const float* b_proj = (const float*)d_in[5];
  const float* w_fc1  = (const float*)d_in[6];
  const float* b_fc1  = (const float*)d_in[7];
  const float* w_fc2  = (const float*)d_in[8];
  const float* b_fc2  = (const float*)d_in[9];
  float* out = (float*)d_out;

  const int M = 8192;
  char* ws = (char*)d_ws;
  ushort* xb     = (ushort*)(ws);               //  4,194,304 B (reused as att)
  ushort* qkv    = (ushort*)(ws + 4194304);     // 12,582,912 B (reused as h)
  ushort* x1b    = (ushort*)(ws + 16777216);    //  4,194,304 B
  ushort* wqkvT  = (ushort*)(ws + 20971520);    //    393,216 B
  ushort* wprojT = (ushort*)(ws + 21364736);    //    131,072 B
  ushort* wfc1T  = (ushort*)(ws + 21495808);    //    262,144 B
  ushort* wfc2T  = (ushort*)(ws + 21757952);    //    262,144 B
  ushort* vT     = (ushort*)(ws + 22020096);    //  4,194,304 B + 64K pad
  ushort* att = xb;                             // xb dead after qkv GEMM
  ushort* h   = qkv;                            // qkv dead after natt

  dim3 blk(256);

  prep_kernel<<<dim3(2560), blk, 0, stream>>>(
      x, w_qkv, w_proj, w_fc1, w_fc2, xb, wqkvT, wprojT, wfc1T, wfc2T);

  // qkv = xb @ wqkvT^T + b_qkv  -> q,k rows + transposed vT
  gemm_stream<0, 256><<<dim3(768 / 64, M / 64), blk, 0, stream>>>(
      xb, wqkvT, b_qkv, nullptr, nullptr, qkv, vT, M, 768);

  natt_mfma<<<dim3(512, 2), blk, 0, stream>>>(qkv, vT, rpb, att);

  // x1b = bf16(att @ wprojT^T + b_proj + x(chw))
  gemm_stream<1, 256><<<dim3(256 / 64, M / 64), blk, 0, stream>>>(
      att, wprojT, b_proj, x, nullptr, x1b, nullptr, M, 256);

  // h = gelu(x1b @ wfc1T^T + b_fc1) -> bf16
  gemm_stream<2, 256><<<dim3(512 / 64, M / 64), blk, 0, stream>>>(
      x1b, wfc1T, b_fc1, nullptr, nullptr, h, nullptr, M, 512);

  // out(chw) = h @ wfc2T^T + b_fc2 + b2f(x1b)
  gemm_stream<3, 512><<<dim3(256 / 64, M / 64), blk, 0, stream>>>(
      h, wfc2T, b_fc2, nullptr, x1b, out, nullptr, M, 256);
}